// Round 11
// baseline (107.295 us; speedup 1.0000x reference)
//
#include <hip/hip_runtime.h>

#define S_LEN   2048
#define BATCH   32
#define NF      1024
#define CTX     20
#define KW      21                 // taps
#define SEGS    16
#define TSEG    (S_LEN / SEGS)     // 128 output rows per segment
#define RSTR    (BATCH * NF)       // floats between consecutive t rows (128 KB)

typedef float f32x4_t __attribute__((ext_vector_type(4)));

// Steady-state streaming-FIR phase (r >= 21 only: all k=0..20 valid since
// output row o = r-k >= 1). P folds to a constant after unroll -> all acc[]
// indices static (rule #20). Reading row r completes out row r-CTX (slot (P+1)%KW).
#define PHASE(P, RB21)                                                          \
    {                                                                           \
        const int r = (RB21) + (P);                                             \
        const int t = t0 + r;                                                   \
        f32x4_t xv;                                                             \
        if (t < S_LEN) xv = *(const f32x4_t*)(xb + (size_t)r * RSTR);           \
        else           xv = (f32x4_t){0.f, 0.f, 0.f, 0.f};  /* zero-pad tail */ \
        _Pragma("unroll")                                                       \
        for (int k = 0; k < KW; ++k) {                                          \
            int s = (P) - k; if (s < 0) s += KW;   /* folds to constant */      \
            acc[s].x = fmaf(xv.x, wk[k].x, acc[s].x);                           \
            acc[s].y = fmaf(xv.y, wk[k].y, acc[s].y);                           \
            acc[s].z = fmaf(xv.z, wk[k].z, acc[s].z);                           \
            acc[s].w = fmaf(xv.w, wk[k].w, acc[s].w);                           \
        }                                                                       \
        {                                                                       \
            const int sc = ((P) + 1) % KW;                                      \
            __builtin_nontemporal_store(acc[sc],                                \
                (f32x4_t*)(ob + (size_t)(r - CTX) * RSTR));                     \
            acc[sc] = (f32x4_t){0.f, 0.f, 0.f, 0.f};                            \
        }                                                                       \
    }

// Warm-up phase r = P = 0..20: only k <= P contribute (output row o = P-k >= 0).
// R10 bug: unconditional k>r terms aliased (mod 21) onto live slots 1..20.
// t = t0+P <= 1920+20 < S_LEN always -> no bounds check needed.
#define PHASE_WARM(P)                                                           \
    {                                                                           \
        f32x4_t xv = *(const f32x4_t*)(xb + (size_t)(P) * RSTR);                \
        _Pragma("unroll")                                                       \
        for (int k = 0; k <= (P); ++k) {                                        \
            acc[(P) - k].x = fmaf(xv.x, wk[k].x, acc[(P) - k].x);               \
            acc[(P) - k].y = fmaf(xv.y, wk[k].y, acc[(P) - k].y);               \
            acc[(P) - k].z = fmaf(xv.z, wk[k].z, acc[(P) - k].z);               \
            acc[(P) - k].w = fmaf(xv.w, wk[k].w, acc[(P) - k].w);               \
        }                                                                       \
        if ((P) == CTX) {   /* r=20 completes out row 0 (slot 0) */             \
            __builtin_nontemporal_store(acc[0], (f32x4_t*)ob);                  \
            acc[0] = (f32x4_t){0.f, 0.f, 0.f, 0.f};                             \
        }                                                                       \
    }

__global__ __launch_bounds__(256)   // no min-waves cap (R2 lesson: cap -> spill)
void lookahead_fir_kernel(const float* __restrict__ x,
                          const float* __restrict__ w,
                          float* __restrict__ out) {
    const int tid = threadIdx.x;      // 0..255: feature group (4 floats each)
    const int seg = blockIdx.x;       // 0..15: t segment
    const int b   = blockIdx.y;       // 0..31
    const int t0  = seg * TSEG;
    const int f   = tid * 4;

    // weights: wk[k] = (w[f+0][k], w[f+1][k], w[f+2][k], w[f+3][k]).
    // Thread's 84 floats are contiguous rows f..f+3 of the (NF,21) matrix.
    f32x4_t wk[KW];
    {
        const float* wp = w + (size_t)f * KW;
        #pragma unroll
        for (int k = 0; k < KW; ++k) {
            wk[k].x = wp[k];
            wk[k].y = wp[KW + k];
            wk[k].z = wp[2 * KW + k];
            wk[k].w = wp[3 * KW + k];
        }
    }

    const float* xb = x   + (size_t)t0 * RSTR + b * NF + f;   // 16B-aligned
    float*       ob = out + (size_t)t0 * RSTR + b * NF + f;

    f32x4_t acc[KW];
    #pragma unroll
    for (int k = 0; k < KW; ++k) acc[k] = (f32x4_t){0.f, 0.f, 0.f, 0.f};

    // ---- warm-up: rows 0..20, masked taps (k <= r) ----
    #pragma unroll
    for (int p = 0; p < KW; ++p) {
        PHASE_WARM(p)
    }

    // ---- steady state: rows 21..146 (6 blocks of 21 phases), then tail 147 ----
    // Outer loop NOT unrolled (I$-friendly); inner 21 phases fully unrolled.
    #pragma unroll 1
    for (int rb = 1; rb < 7; ++rb) {
        const int rb21 = rb * KW;
        #pragma unroll
        for (int p = 0; p < KW; ++p) {
            PHASE(p, rb21)
        }
    }
    PHASE(0, 147)   // completes out row 127 (slot 1); dead-slot FMAs harmless
}

extern "C" void kernel_launch(void* const* d_in, const int* in_sizes, int n_in,
                              void* d_out, int out_size, void* d_ws, size_t ws_size,
                              hipStream_t stream) {
    const float* x = (const float*)d_in[0];
    const float* w = (const float*)d_in[1];
    float* out     = (float*)d_out;

    dim3 grid(SEGS, BATCH);   // (16, 32) = 512 blocks, ~2/CU (VGPR-capped 8 waves)
    dim3 block(256);
    lookahead_fir_kernel<<<grid, block, 0, stream>>>(x, w, out);
}